// Round 3
// baseline (1168.207 us; speedup 1.0000x reference)
//
#include <hip/hip_runtime.h>

typedef unsigned short u16;
typedef unsigned int u32;

#define NB   128
#define NT   1024
#define NENC 768
#define NH   256
#define NMELS 400

// ---- workspace layout (float offsets); total ~286K floats = 1.15 MB ----
constexpr int OFF_FLAG  = 0;                      // int mode at ws[0]
constexpr int OFF_HATTN = 16;                     // 128*256 fp32 h_att_n
constexpr int OFF_G     = OFF_HATTN + NB*NH;      // 128*168 dynamic filters
constexpr int OFF_ALPHA = OFF_G + NB*168;         // 128*1024 fp32 alpha
constexpr int OFF_DCS   = OFF_ALPHA + NB*NT;      // 128*768 fp32 dcs accumulator
constexpr int OFF_UT    = OFF_DCS + NB*NENC;      // 128*16 [Uw|Tw]
constexpr int OFF_TBF   = OFF_UT + 2048;          // 128
constexpr int OFF_VWF   = OFF_TBF + 128;          // 128
constexpr int OFF_FKF   = OFF_VWF + 128;          // 168
constexpr int OFF_PF    = OFF_FKF + 168;          // 11

// ---- output layout (elements, concatenated in return order) ----
constexpr int OUT_MEL   = 0;                      // 128*400
constexpr int OUT_ALPHA = OUT_MEL + NB*NMELS;     // 128*1024
constexpr int OUT_DCS   = OUT_ALPHA + NB*NT;      // 128*768
constexpr int OUT_HATT  = OUT_DCS + NB*NENC;      // 128*256
constexpr int OUT_H1    = OUT_HATT + NB*NH;       // 128*256
constexpr int OUT_H2    = OUT_H1 + NB*NH;         // 128*256

__device__ __forceinline__ float bfd(u16 u){ u32 x = ((u32)u) << 16; return __builtin_bit_cast(float, x); }
__device__ __forceinline__ float bflo(u32 u){ return __builtin_bit_cast(float, u << 16); }
__device__ __forceinline__ float bfhi(u32 u){ return __builtin_bit_cast(float, u & 0xffff0000u); }
__device__ __forceinline__ u16 f2bf(float f){
  u32 x = __builtin_bit_cast(u32, f);
  u32 r = x + 0x7fffu + ((x >> 16) & 1u);   // RNE
  return (u16)(r >> 16);
}
__device__ __forceinline__ float sigm(float x){ return 1.f / (1.f + __expf(-x)); }
__device__ __forceinline__ float tanh_(float x){
  float e = __expf(2.f * x);
  return 1.f - 2.f / (e + 1.f);
}

// M=1: bf16 storage; M=0: fp32 storage
template<int M> __device__ __forceinline__ float ld1(const void* p, size_t i){
  if constexpr (M) return bfd(((const u16*)p)[i]);
  else return ((const float*)p)[i];
}
template<int M> __device__ __forceinline__ float2 ldpair(const void* p, size_t k2){
  if constexpr (M){ u32 u = ((const u32*)p)[k2]; float2 r; r.x = bflo(u); r.y = bfhi(u); return r; }
  else return ((const float2*)p)[k2];
}
template<int M> __device__ __forceinline__ float4 ldquad(const void* p, size_t q){ // elems 4q..4q+3
  if constexpr (M){
    uint2 u = ((const uint2*)p)[q];
    float4 r; r.x = bflo(u.x); r.y = bfhi(u.x); r.z = bflo(u.y); r.w = bfhi(u.y); return r;
  } else return ((const float4*)p)[q];
}
template<int M> __device__ __forceinline__ void st1(void* p, size_t i, float v){
  if constexpr (M) ((u16*)p)[i] = f2bf(v);
  else ((float*)p)[i] = v;
}

// butterfly reduce across wave64 (all lanes get the sum)
__device__ __forceinline__ float wred(float v){
  #pragma unroll
  for (int off = 1; off < 64; off <<= 1) v += __shfl_xor(v, off);
  return v;
}

// wave-cooperative dot: 64 lanes span K (K2 = K/2 element-pairs), weight row
// read coalesced (lane l reads pairs l, l+64, ...), x from LDS (fp32).
template<int M, int K2>
__device__ __forceinline__ float wdot(const void* W, size_t row, const float* x, int l){
  float a = 0.f;
  #pragma unroll
  for (int p0 = 0; p0 < K2; p0 += 64){
    int p = p0 + l;
    if (K2 % 64 == 0 || p < K2){
      float2 w = ldpair<M>(W, row * K2 + p);
      a = fmaf(x[2 * p], w.x, fmaf(x[2 * p + 1], w.y, a));
    }
  }
  return a;
}

// GRU output unit j via wave-cooperative dots; returns h'[j] (valid in all lanes)
template<int M, int KX2>
__device__ __forceinline__ float gru_wave(const float* xs, const float* hs,
    const void* wih, const void* whh, const void* bih, const void* bhh, int j, int l){
  float ir = wdot<M, KX2>(wih, j, xs, l);
  float iz = wdot<M, KX2>(wih, 256 + j, xs, l);
  float in_ = wdot<M, KX2>(wih, 512 + j, xs, l);
  float hr = wdot<M, 128>(whh, j, hs, l);
  float hz = wdot<M, 128>(whh, 256 + j, hs, l);
  float hn = wdot<M, 128>(whh, 512 + j, hs, l);
  ir = wred(ir); iz = wred(iz); in_ = wred(in_);
  hr = wred(hr); hz = wred(hz); hn = wred(hn);
  float r = sigm(ir + ld1<M>(bih, j) + hr + ld1<M>(bhh, j));
  float z = sigm(iz + ld1<M>(bih, 256 + j) + hz + ld1<M>(bhh, 256 + j));
  float n = tanh_(in_ + ld1<M>(bih, 512 + j) + r * (hn + ld1<M>(bhh, 512 + j)));
  return (1.f - z) * n + z * hs[j];
}

// ---- kernel 0: dtype detection + unpack tiny DCA weights to fp32 ----
template<int M>
__device__ __forceinline__ void prep_body(const void* Uw, const void* Tw, const void* Tb,
    const void* vw, const void* Fk, const void* P, float* ws, int j){
  for (int i = j; i < 2048; i += 256){
    int m = i >> 4, c = i & 15;
    ws[OFF_UT + i] = (c < 8) ? ld1<M>(Uw, m * 8 + c) : ld1<M>(Tw, m * 8 + (c - 8));
  }
  if (j < 128){ ws[OFF_TBF + j] = ld1<M>(Tb, j); ws[OFF_VWF + j] = ld1<M>(vw, j); }
  if (j < 168) ws[OFF_FKF + j] = ld1<M>(Fk, j);
  if (j < 11)  ws[OFF_PF + j]  = ld1<M>(P, j);
}

__global__ void prep_kernel(const void* enc, const void* Uw, const void* Tw, const void* Tb,
                            const void* vw, const void* Fk, const void* P, float* ws){
  int j = threadIdx.x;  // 256
  __shared__ int cnt;
  if (j == 0) cnt = 0;
  __syncthreads();
  // bf16 storage: low u16 of each u32 is a small bf16 (exp <= ~0x85 for N(0,1));
  // fp32 storage: low 16 bits ~uniform -> ~25% have bf16-exponent >= 0xC0.
  int c = 0;
  const u32* ep = (const u32*)enc;
  for (int i = j; i < 1024; i += 256){
    u32 w = ep[i] & 0xffffu;
    int ex = (int)((w >> 7) & 0xff);
    if (ex >= 0xC0) c++;
  }
  if (c) atomicAdd(&cnt, c);
  __syncthreads();
  int mode = (cnt > 8) ? 0 : 1;   // 1 = bf16, 0 = fp32
  if (j == 0) ((int*)ws)[OFF_FLAG] = mode;
  if (mode) prep_body<1>(Uw, Tw, Tb, vw, Fk, P, ws, j);
  else      prep_body<0>(Uw, Tw, Tb, vw, Fk, P, ws, j);
}

// ---- kernel 1: prenet + attention GRU + dynamic filter G (one block per b) ----
// All GEMVs wave-cooperative: coalesced weight-row reads, shuffle reduce.
template<int M>
__device__ __forceinline__ void head_body(const void* prev_frame, const void* dcs_state,
    const void* h_att, const void* pre_w1, const void* pre_b1, const void* pre_w2, const void* pre_b2,
    const void* att_wih, const void* att_whh, const void* att_bih, const void* att_bhh,
    const void* Ww, const void* Wb, const void* Vw,
    float* ws, void* out, float* sm){
  float* pf = sm;            // 400
  float* o1 = sm + 400;      // 256
  float* xc = sm + 656;      // 896
  float* hv = sm + 1552;     // 256
  float* hn = sm + 1808;     // 256
  float* t1 = sm + 2064;     // 128
  int b = blockIdx.x, tid = threadIdx.x;
  int w = tid >> 6, l = tid & 63;
  for (int p = tid; p < 200; p += 256){ float2 v = ldpair<M>(prev_frame, (size_t)b * 200 + p); pf[2*p] = v.x; pf[2*p+1] = v.y; }
  for (int p = tid; p < 384; p += 256){ float2 v = ldpair<M>(dcs_state, (size_t)b * 384 + p); xc[2*p] = v.x; xc[2*p+1] = v.y; }
  if (tid < 128){ float2 v = ldpair<M>(h_att, (size_t)b * 128 + tid); hv[2*tid] = v.x; hv[2*tid+1] = v.y; }
  __syncthreads();
  // prenet1: 256 outputs, K=400
  for (int j = w; j < 256; j += 4){
    float a = wred(wdot<M, 200>(pre_w1, j, pf, l));
    if (l == 0) o1[j] = fmaxf(a + ld1<M>(pre_b1, j), 0.f);
  }
  __syncthreads();
  // prenet2: 128 outputs, K=256 -> xc[768..896)
  for (int j = w; j < 128; j += 4){
    float a = wred(wdot<M, 128>(pre_w2, j, o1, l));
    if (l == 0) xc[768 + j] = fmaxf(a + ld1<M>(pre_b2, j), 0.f);
  }
  __syncthreads();
  // attention GRU: 256 outputs, Kx=896
  for (int j = w; j < 256; j += 4){
    float hnew = gru_wave<M, 448>(xc, hv, att_wih, att_whh, att_bih, att_bhh, j, l);
    if (l == 0){
      hn[j] = hnew;
      ws[OFF_HATTN + b * 256 + j] = hnew;
    }
    if (l == 1) st1<M>(out, OUT_HATT + (size_t)b * 256 + j, hnew);
  }
  __syncthreads();
  // t1 = tanh(h' @ Ww^T + Wb): 128 outputs, K=256
  for (int j = w; j < 128; j += 4){
    float a = wred(wdot<M, 128>(Ww, j, hn, l));
    if (l == 0) t1[j] = tanh_(a + ld1<M>(Wb, j));
  }
  __syncthreads();
  // G = t1 @ Vw^T: 168 outputs, K=128
  for (int j = w; j < 168; j += 4){
    float a = wred(wdot<M, 64>(Vw, j, t1, l));
    if (l == 0) ws[OFF_G + b * 168 + j] = a;
  }
}

__global__ __launch_bounds__(256)
void head_kernel(const void* prev_frame, const void* dcs_state, const void* h_att,
    const void* pre_w1, const void* pre_b1, const void* pre_w2, const void* pre_b2,
    const void* att_wih, const void* att_whh, const void* att_bih, const void* att_bhh,
    const void* Ww, const void* Wb, const void* Vw, float* ws, void* out){
  __shared__ float sm[2192];
  if (((const int*)ws)[OFF_FLAG])
    head_body<1>(prev_frame, dcs_state, h_att, pre_w1, pre_b1, pre_w2, pre_b2,
                 att_wih, att_whh, att_bih, att_bhh, Ww, Wb, Vw, ws, out, sm);
  else
    head_body<0>(prev_frame, dcs_state, h_att, pre_w1, pre_b1, pre_w2, pre_b2,
                 att_wih, att_whh, att_bih, att_bhh, Ww, Wb, Vw, ws, out, sm);
}

// ---- kernel 2: DCA energies + softmax (one block per b); also zeroes dcs acc ----
template<int M>
__device__ __forceinline__ void dca_body(const void* prev_att, const float* __restrict__ wsc,
                                         float* ws, void* out, float* sm){
  float* apad = sm;            // 1044
  float* red  = sm + 1044;     // 16
  float* bc   = sm + 1060;     // 2
  int b = blockIdx.x, t = threadIdx.x;
  if (t < NENC) ws[OFF_DCS + b * NENC + t] = 0.f;   // zero dcs accumulator
  if (t < 10){ apad[t] = 0.f; apad[NT + 10 + t] = 0.f; }
  if (t < 512){ float2 v = ldpair<M>(prev_att, (size_t)b * 512 + t); apad[10 + 2*t] = v.x; apad[10 + 2*t + 1] = v.y; }
  __syncthreads();
  float ap[21];
  #pragma unroll
  for (int k = 0; k < 21; k++) ap[k] = apad[t + k];
  const float* Pw = wsc + OFF_PF;
  float pv = 0.f;
  #pragma unroll
  for (int jj = 0; jj < 11; jj++) pv = fmaf(Pw[jj], ap[jj], pv);
  pv = __logf(fmaxf(pv, 1e-6f));
  const float* Fw = wsc + OFF_FKF;
  const float* Gw = wsc + OFF_G + b * 168;
  float fg[16];
  #pragma unroll
  for (int c = 0; c < 8; c++){
    float fa = 0.f, ga = 0.f;
    #pragma unroll
    for (int k = 0; k < 21; k++){
      fa = fmaf(Fw[c * 21 + k], ap[k], fa);
      ga = fmaf(Gw[c * 21 + k], ap[k], ga);
    }
    fg[c] = fa; fg[8 + c] = ga;
  }
  const float* UT  = wsc + OFF_UT;
  const float* Tbf = wsc + OFF_TBF;
  const float* vwf = wsc + OFF_VWF;
  float e = pv;
  #pragma unroll 4
  for (int m = 0; m < 128; m++){
    float h = Tbf[m];
    #pragma unroll
    for (int c = 0; c < 16; c++) h = fmaf(UT[m * 16 + c], fg[c], h);
    e = fmaf(vwf[m], tanh_(h), e);
  }
  float mx = e;
  #pragma unroll
  for (int off = 1; off < 64; off <<= 1) mx = fmaxf(mx, __shfl_xor(mx, off));
  if ((t & 63) == 0) red[t >> 6] = mx;
  __syncthreads();
  if (t == 0){ float m2 = red[0]; for (int i = 1; i < 16; i++) m2 = fmaxf(m2, red[i]); bc[0] = m2; }
  __syncthreads();
  float ex = __expf(e - bc[0]);
  float smv = ex;
  #pragma unroll
  for (int off = 1; off < 64; off <<= 1) smv += __shfl_xor(smv, off);
  if ((t & 63) == 0) red[t >> 6] = smv;
  __syncthreads();
  if (t == 0){ float s2 = 0.f; for (int i = 0; i < 16; i++) s2 += red[i]; bc[1] = s2; }
  __syncthreads();
  float al = ex / bc[1];
  ws[OFF_ALPHA + b * NT + t] = al;
  st1<M>(out, OUT_ALPHA + (size_t)b * NT + t, al);
}

__global__ __launch_bounds__(1024)
void dca_e_kernel(const void* prev_att, float* ws, void* out){
  __shared__ float sm[1062];
  if (((const int*)ws)[OFF_FLAG]) dca_body<1>(prev_att, ws, ws, out, sm);
  else                            dca_body<0>(prev_att, ws, ws, out, sm);
}

// ---- kernel 3: dcs (HBM-bound): grid (8 chunks, 128 b), 192 thr x 4 cols, atomicAdd ----
template<int M>
__device__ __forceinline__ void dcs_body(const void* enc, float* ws, float* sA){
  int ch = blockIdx.x, b = blockIdx.y, j = threadIdx.x;
  int t0 = ch * 128;
  if (j < 128) sA[j] = ws[OFF_ALPHA + b * NT + t0 + j];
  __syncthreads();
  float a0 = 0.f, a1 = 0.f, a2 = 0.f, a3 = 0.f;
  size_t qbase = (size_t)(b * NT + t0) * (NENC / 4) + j;   // quad index, 192 quads/row
  #pragma unroll 4
  for (int tl = 0; tl < 128; tl++){
    float a = sA[tl];
    float4 q = ldquad<M>(enc, qbase + (size_t)tl * (NENC / 4));
    a0 = fmaf(a, q.x, a0);
    a1 = fmaf(a, q.y, a1);
    a2 = fmaf(a, q.z, a2);
    a3 = fmaf(a, q.w, a3);
  }
  float* o = ws + OFF_DCS + (size_t)b * NENC + 4 * j;
  atomicAdd(o + 0, a0);
  atomicAdd(o + 1, a1);
  atomicAdd(o + 2, a2);
  atomicAdd(o + 3, a3);
}

__global__ __launch_bounds__(192)
void dcs_kernel(const void* enc, float* ws){
  __shared__ float sA[128];
  if (((const int*)ws)[OFF_FLAG]) dcs_body<1>(enc, ws, sA);
  else                            dcs_body<0>(enc, ws, sA);
}

// ---- kernel 4: dcs out + lin + GRU1 + GRU2 + proj (one block per b) ----
template<int M>
__device__ __forceinline__ void tail_body(float* ws,
    const void* lin_w, const void* lin_b,
    const void* r1_wih, const void* r1_whh, const void* r1_bih, const void* r1_bhh,
    const void* r2_wih, const void* r2_whh, const void* r2_bih, const void* r2_bhh,
    const void* proj_w, const void* proj_b,
    const void* h1_in, const void* h2_in, void* out, float* sm){
  float* xc  = sm;            // 1024
  float* sx  = sm + 1024;     // 256
  float* sx2 = sm + 1280;     // 256
  float* sx3 = sm + 1536;     // 256
  float* h1s = sm + 1792;     // 256
  float* h2s = sm + 2048;     // 256
  int b = blockIdx.x, tid = threadIdx.x;
  int w = tid >> 6, l = tid & 63;
  for (int k = tid; k < NENC; k += 256){
    float s = ws[OFF_DCS + (size_t)b * NENC + k];
    xc[k] = s;
    st1<M>(out, OUT_DCS + (size_t)b * NENC + k, s);
  }
  xc[768 + tid] = ws[OFF_HATTN + b * 256 + tid];
  if (tid < 128){
    float2 v = ldpair<M>(h1_in, (size_t)b * 128 + tid); h1s[2*tid] = v.x; h1s[2*tid+1] = v.y;
    float2 u = ldpair<M>(h2_in, (size_t)b * 128 + tid); h2s[2*tid] = u.x; h2s[2*tid+1] = u.y;
  }
  __syncthreads();
  // lin: 256 outputs, K=1024
  for (int j = w; j < 256; j += 4){
    float a = wred(wdot<M, 512>(lin_w, j, xc, l));
    if (l == 0) sx[j] = a + ld1<M>(lin_b, j);
  }
  __syncthreads();
  // GRU1 (Kx=256)
  for (int j = w; j < 256; j += 4){
    float h1n = gru_wave<M, 128>(sx, h1s, r1_wih, r1_whh, r1_bih, r1_bhh, j, l);
    if (l == 0) sx2[j] = sx[j] + h1n;
    if (l == 1) st1<M>(out, OUT_H1 + (size_t)b * 256 + j, h1n);
  }
  __syncthreads();
  // GRU2 (Kx=256)
  for (int j = w; j < 256; j += 4){
    float h2n = gru_wave<M, 128>(sx2, h2s, r2_wih, r2_whh, r2_bih, r2_bhh, j, l);
    if (l == 0) sx3[j] = sx2[j] + h2n;
    if (l == 1) st1<M>(out, OUT_H2 + (size_t)b * 256 + j, h2n);
  }
  __syncthreads();
  // proj: 400 outputs, K=256
  for (int j = w; j < 400; j += 4){
    float a = wred(wdot<M, 128>(proj_w, j, sx3, l));
    if (l == 0) st1<M>(out, OUT_MEL + (size_t)b * NMELS + j, a + ld1<M>(proj_b, j));
  }
}

__global__ __launch_bounds__(256)
void tail_kernel(float* ws,
    const void* lin_w, const void* lin_b,
    const void* r1_wih, const void* r1_whh, const void* r1_bih, const void* r1_bhh,
    const void* r2_wih, const void* r2_whh, const void* r2_bih, const void* r2_bhh,
    const void* proj_w, const void* proj_b,
    const void* h1_in, const void* h2_in, void* out){
  __shared__ float sm[2304];
  if (((const int*)ws)[OFF_FLAG])
    tail_body<1>(ws, lin_w, lin_b, r1_wih, r1_whh, r1_bih, r1_bhh,
                 r2_wih, r2_whh, r2_bih, r2_bhh, proj_w, proj_b, h1_in, h2_in, out, sm);
  else
    tail_body<0>(ws, lin_w, lin_b, r1_wih, r1_whh, r1_bih, r1_bhh,
                 r2_wih, r2_whh, r2_bih, r2_bhh, proj_w, proj_b, h1_in, h2_in, out, sm);
}

extern "C" void kernel_launch(void* const* d_in, const int* in_sizes, int n_in,
                              void* d_out, int out_size, void* d_ws, size_t ws_size,
                              hipStream_t stream){
  (void)in_sizes; (void)n_in; (void)out_size; (void)ws_size;
  const void* enc       = d_in[0];
  const void* prev_frame= d_in[1];
  const void* prev_att  = d_in[2];
  const void* dcs_state = d_in[3];
  const void* h_att     = d_in[4];
  const void* h1        = d_in[5];
  const void* h2        = d_in[6];
  const void* pre_w1    = d_in[7];
  const void* pre_b1    = d_in[8];
  const void* pre_w2    = d_in[9];
  const void* pre_b2    = d_in[10];
  const void* dca_Ww    = d_in[11];
  const void* dca_Wb    = d_in[12];
  const void* dca_Vw    = d_in[13];
  const void* dca_Fk    = d_in[14];
  const void* dca_Uw    = d_in[15];
  const void* dca_Tw    = d_in[16];
  const void* dca_Tb    = d_in[17];
  const void* dca_vw    = d_in[18];
  const void* att_wih   = d_in[19];
  const void* att_whh   = d_in[20];
  const void* att_bih   = d_in[21];
  const void* att_bhh   = d_in[22];
  const void* lin_w     = d_in[23];
  const void* lin_b     = d_in[24];
  const void* r1_wih    = d_in[25];
  const void* r1_whh    = d_in[26];
  const void* r1_bih    = d_in[27];
  const void* r1_bhh    = d_in[28];
  const void* r2_wih    = d_in[29];
  const void* r2_whh    = d_in[30];
  const void* r2_bih    = d_in[31];
  const void* r2_bhh    = d_in[32];
  const void* proj_w    = d_in[33];
  const void* proj_b    = d_in[34];
  const void* P         = d_in[35];
  float* ws = (float*)d_ws;
  void* out = d_out;

  prep_kernel<<<1, 256, 0, stream>>>(enc, dca_Uw, dca_Tw, dca_Tb, dca_vw, dca_Fk, P, ws);
  head_kernel<<<NB, 256, 0, stream>>>(prev_frame, dcs_state, h_att,
      pre_w1, pre_b1, pre_w2, pre_b2,
      att_wih, att_whh, att_bih, att_bhh,
      dca_Ww, dca_Wb, dca_Vw, ws, out);
  dca_e_kernel<<<NB, 1024, 0, stream>>>(prev_att, ws, out);
  dcs_kernel<<<dim3(8, NB), 192, 0, stream>>>(enc, ws);
  tail_kernel<<<NB, 256, 0, stream>>>(ws, lin_w, lin_b,
      r1_wih, r1_whh, r1_bih, r1_bhh,
      r2_wih, r2_whh, r2_bih, r2_bhh,
      proj_w, proj_b, h1, h2, out);
}

// Round 4
// 819.322 us; speedup vs baseline: 1.4258x; 1.4258x over previous
//
#include <hip/hip_runtime.h>

typedef unsigned short u16;
typedef unsigned int u32;

#define NB   128
#define NT   1024
#define NENC 768
#define NH   256
#define NMELS 400

// ---- workspace layout (float offsets) ----
constexpr int OFF_FLAG  = 0;                      // int mode at ws[0]
constexpr int OFF_HATTN = 16;                     // 128*256 fp32 h_att_n
constexpr int OFF_G     = OFF_HATTN + NB*NH;      // 128*168 dynamic filters
constexpr int OFF_ALPHA = OFF_G + NB*168;         // 128*1024 fp32 alpha
constexpr int OFF_DCS   = OFF_ALPHA + NB*NT;      // 128*768 fp32 dcs accumulator
constexpr int OFF_UT    = OFF_DCS + NB*NENC;      // 128*16 [Uw|Tw]
constexpr int OFF_TBF   = OFF_UT + 2048;          // 128
constexpr int OFF_VWF   = OFF_TBF + 128;          // 128
constexpr int OFF_FKF   = OFF_VWF + 128;          // 168
constexpr int OFF_PF    = OFF_FKF + 168;          // 16 (11 used)
constexpr int OFF_O1    = OFF_PF + 16;            // 128*256 prenet1 out
constexpr int OFF_O2    = OFF_O1 + NB*256;        // 128*128 prenet2 out
constexpr int OFF_T1    = OFF_O2 + NB*128;        // 128*128 tanh(Ww h')
constexpr int OFF_SX    = OFF_T1 + NB*128;        // 128*256 lin out
constexpr int OFF_SX2   = OFF_SX + NB*256;        // 128*256 x + h1n
constexpr int OFF_SX3   = OFF_SX2 + NB*256;       // 128*256 x2 + h2n

// ---- output layout (elements, concatenated in return order) ----
constexpr int OUT_MEL   = 0;                      // 128*400
constexpr int OUT_ALPHA = OUT_MEL + NB*NMELS;     // 128*1024
constexpr int OUT_DCS   = OUT_ALPHA + NB*NT;      // 128*768
constexpr int OUT_HATT  = OUT_DCS + NB*NENC;      // 128*256
constexpr int OUT_H1    = OUT_HATT + NB*NH;       // 128*256
constexpr int OUT_H2    = OUT_H1 + NB*NH;         // 128*256

__device__ __forceinline__ float bfd(u16 u){ u32 x = ((u32)u) << 16; return __builtin_bit_cast(float, x); }
__device__ __forceinline__ float bflo(u32 u){ return __builtin_bit_cast(float, u << 16); }
__device__ __forceinline__ float bfhi(u32 u){ return __builtin_bit_cast(float, u & 0xffff0000u); }
__device__ __forceinline__ u16 f2bf(float f){
  u32 x = __builtin_bit_cast(u32, f);
  u32 r = x + 0x7fffu + ((x >> 16) & 1u);   // RNE
  return (u16)(r >> 16);
}
__device__ __forceinline__ float sigm(float x){ return 1.f / (1.f + __expf(-x)); }
__device__ __forceinline__ float tanh_(float x){
  float e = __expf(2.f * x);
  return 1.f - 2.f / (e + 1.f);
}

// M=1: bf16 storage; M=0: fp32 storage
template<int M> __device__ __forceinline__ float ld1(const void* p, size_t i){
  if constexpr (M) return bfd(((const u16*)p)[i]);
  else return ((const float*)p)[i];
}
template<int M> __device__ __forceinline__ float2 ldpair(const void* p, size_t k2){
  if constexpr (M){ u32 u = ((const u32*)p)[k2]; float2 r; r.x = bflo(u); r.y = bfhi(u); return r; }
  else return ((const float2*)p)[k2];
}
template<int M> __device__ __forceinline__ float4 ldquad(const void* p, size_t q){
  if constexpr (M){
    uint2 u = ((const uint2*)p)[q];
    float4 r; r.x = bflo(u.x); r.y = bfhi(u.x); r.z = bflo(u.y); r.w = bfhi(u.y); return r;
  } else return ((const float4*)p)[q];
}
template<int M> __device__ __forceinline__ void st1(void* p, size_t i, float v){
  if constexpr (M) ((u16*)p)[i] = f2bf(v);
  else ((float*)p)[i] = v;
}

// Single dot with 4 independent accumulators. W row uniform (j=blockIdx) ->
// broadcast/scalar loads; x per-lane row (lane=b), L1-resident across k.
template<int MW, int MX, int K2>
__device__ __forceinline__ float dot4(const void* __restrict__ W, size_t wr,
                                      const void* __restrict__ x, size_t xb){
  float acc[4] = {0.f, 0.f, 0.f, 0.f};
  #pragma unroll 4
  for (int k2 = 0; k2 < K2; k2 += 4){
    #pragma unroll
    for (int u = 0; u < 4; u++){
      float2 w = ldpair<MW>(W, wr + k2 + u);
      float2 xv = ldpair<MX>(x, xb + k2 + u);
      acc[u] = fmaf(xv.x, w.x, fmaf(xv.y, w.y, acc[u]));
    }
  }
  return (acc[0] + acc[1]) + (acc[2] + acc[3]);
}

// Triple dot (3 gate rows share x) — 3 independent FMA chains
template<int MW, int MX, int K2>
__device__ __forceinline__ void dot3(const void* __restrict__ W, size_t r0, size_t r1, size_t r2,
                                     const void* __restrict__ x, size_t xb,
                                     float& d0, float& d1, float& d2){
  #pragma unroll 4
  for (int k2 = 0; k2 < K2; k2++){
    float2 xv = ldpair<MX>(x, xb + k2);
    float2 w0 = ldpair<MW>(W, r0 + k2);
    float2 w1 = ldpair<MW>(W, r1 + k2);
    float2 w2 = ldpair<MW>(W, r2 + k2);
    d0 = fmaf(xv.x, w0.x, fmaf(xv.y, w0.y, d0));
    d1 = fmaf(xv.x, w1.x, fmaf(xv.y, w1.y, d1));
    d2 = fmaf(xv.x, w2.x, fmaf(xv.y, w2.y, d2));
  }
}

#define MODE_DISPATCH(body_call_1, body_call_0, wsptr) \
  if (((const int*)(wsptr))[OFF_FLAG]) { body_call_1; } else { body_call_0; }

// ---- kernel 0: dtype detection + unpack tiny DCA weights to fp32 ----
template<int M>
__device__ __forceinline__ void prep_body(const void* Uw, const void* Tw, const void* Tb,
    const void* vw, const void* Fk, const void* P, float* ws, int j){
  for (int i = j; i < 2048; i += 256){
    int m = i >> 4, c = i & 15;
    ws[OFF_UT + i] = (c < 8) ? ld1<M>(Uw, m * 8 + c) : ld1<M>(Tw, m * 8 + (c - 8));
  }
  if (j < 128){ ws[OFF_TBF + j] = ld1<M>(Tb, j); ws[OFF_VWF + j] = ld1<M>(vw, j); }
  if (j < 168) ws[OFF_FKF + j] = ld1<M>(Fk, j);
  if (j < 11)  ws[OFF_PF + j]  = ld1<M>(P, j);
}

__global__ void prep_kernel(const void* enc, const void* Uw, const void* Tw, const void* Tb,
                            const void* vw, const void* Fk, const void* P, float* ws){
  int j = threadIdx.x;  // 256
  __shared__ int cnt;
  if (j == 0) cnt = 0;
  __syncthreads();
  int c = 0;
  const u32* ep = (const u32*)enc;
  for (int i = j; i < 1024; i += 256){
    u32 w = ep[i] & 0xffffu;
    int ex = (int)((w >> 7) & 0xff);
    if (ex >= 0xC0) c++;
  }
  if (c) atomicAdd(&cnt, c);
  __syncthreads();
  int mode = (cnt > 8) ? 0 : 1;   // 1 = bf16, 0 = fp32
  if (j == 0) ((int*)ws)[OFF_FLAG] = mode;
  if (mode) prep_body<1>(Uw, Tw, Tb, vw, Fk, P, ws, j);
  else      prep_body<0>(Uw, Tw, Tb, vw, Fk, P, ws, j);
}

// ---- prenet1: o1[b][j] = relu(prev_frame[b] . w1[j] + b1[j]); grid 256, block 128 ----
template<int M>
__device__ __forceinline__ void pre1_body(const void* __restrict__ x, const void* __restrict__ W,
                                          const void* __restrict__ bias, float* ws){
  int j = blockIdx.x, b = threadIdx.x;
  float a = dot4<M, M, 200>(W, (size_t)j * 200, x, (size_t)b * 200) + ld1<M>(bias, j);
  ws[OFF_O1 + b * 256 + j] = fmaxf(a, 0.f);
}
__global__ __launch_bounds__(128)
void pre1_kernel(const void* x, const void* W, const void* bias, float* ws){
  MODE_DISPATCH(pre1_body<1>(x, W, bias, ws), pre1_body<0>(x, W, bias, ws), ws)
}

// ---- prenet2: o2[b][j] = relu(o1[b] . w2[j] + b2[j]); grid 128, block 128 ----
template<int M>
__device__ __forceinline__ void pre2_body(const void* __restrict__ W, const void* __restrict__ bias, float* ws){
  int j = blockIdx.x, b = threadIdx.x;
  float a = dot4<M, 0, 128>(W, (size_t)j * 128, ws + OFF_O1, (size_t)b * 128) + ld1<M>(bias, j);
  ws[OFF_O2 + b * 128 + j] = fmaxf(a, 0.f);
}
__global__ __launch_bounds__(128)
void pre2_kernel(const void* W, const void* bias, float* ws){
  MODE_DISPATCH(pre2_body<1>(W, bias, ws), pre2_body<0>(W, bias, ws), ws)
}

// ---- attention GRU: grid 256 (j), block 128 (b); x = [dcs_state(768), o2(128)] ----
template<int M>
__device__ __forceinline__ void gru_att_body(const void* __restrict__ xg, const void* __restrict__ h,
    const void* __restrict__ wih, const void* __restrict__ whh,
    const void* __restrict__ bih, const void* __restrict__ bhh,
    float* ws, void* out){
  int j = blockIdx.x, b = threadIdx.x;
  float ir = 0.f, iz = 0.f, in_ = 0.f, hr = 0.f, hz = 0.f, hn = 0.f;
  size_t r0 = (size_t)j * 448, r1 = (size_t)(256 + j) * 448, r2 = (size_t)(512 + j) * 448;
  dot3<M, M, 384>(wih, r0, r1, r2, xg, (size_t)b * 384, ir, iz, in_);
  dot3<M, 0, 64>(wih, r0 + 384, r1 + 384, r2 + 384, ws + OFF_O2, (size_t)b * 64, ir, iz, in_);
  dot3<M, M, 128>(whh, (size_t)j * 128, (size_t)(256 + j) * 128, (size_t)(512 + j) * 128,
                  h, (size_t)b * 128, hr, hz, hn);
  float r = sigm(ir + ld1<M>(bih, j) + hr + ld1<M>(bhh, j));
  float z = sigm(iz + ld1<M>(bih, 256 + j) + hz + ld1<M>(bhh, 256 + j));
  float n = tanh_(in_ + ld1<M>(bih, 512 + j) + r * (hn + ld1<M>(bhh, 512 + j)));
  float hv = ld1<M>(h, (size_t)b * 256 + j);
  float hnew = (1.f - z) * n + z * hv;
  ws[OFF_HATTN + b * 256 + j] = hnew;
  st1<M>(out, OUT_HATT + (size_t)b * 256 + j, hnew);
}
__global__ __launch_bounds__(128)
void gru_att_kernel(const void* xg, const void* h, const void* wih, const void* whh,
                    const void* bih, const void* bhh, float* ws, void* out){
  MODE_DISPATCH(gru_att_body<1>(xg, h, wih, whh, bih, bhh, ws, out),
                gru_att_body<0>(xg, h, wih, whh, bih, bhh, ws, out), ws)
}

// ---- t1 = tanh(h' @ Ww^T + Wb); grid 128, block 128 ----
template<int M>
__device__ __forceinline__ void ww_body(const void* __restrict__ W, const void* __restrict__ bias, float* ws){
  int j = blockIdx.x, b = threadIdx.x;
  float a = dot4<M, 0, 128>(W, (size_t)j * 128, ws + OFF_HATTN, (size_t)b * 128) + ld1<M>(bias, j);
  ws[OFF_T1 + b * 128 + j] = tanh_(a);
}
__global__ __launch_bounds__(128)
void ww_kernel(const void* W, const void* bias, float* ws){
  MODE_DISPATCH(ww_body<1>(W, bias, ws), ww_body<0>(W, bias, ws), ws)
}

// ---- G = t1 @ Vw^T; grid 168, block 128 ----
template<int M>
__device__ __forceinline__ void vw_body(const void* __restrict__ W, float* ws){
  int j = blockIdx.x, b = threadIdx.x;
  float a = dot4<M, 0, 64>(W, (size_t)j * 64, ws + OFF_T1, (size_t)b * 64);
  ws[OFF_G + b * 168 + j] = a;
}
__global__ __launch_bounds__(128)
void vw_kernel(const void* W, float* ws){
  MODE_DISPATCH(vw_body<1>(W, ws), vw_body<0>(W, ws), ws)
}

// ---- DCA energies + softmax (one block per b); zeroes dcs acc; LDS-staged consts ----
template<int M>
__device__ __forceinline__ void dca_body(const void* prev_att, const float* __restrict__ wsc,
                                         float* ws, void* out, float* sm){
  float* apad = sm;            // 1044
  float* red  = sm + 1044;     // 16
  float* bc   = sm + 1060;     // 2
  float* sUT  = sm + 1062;     // 2048
  float* sTb  = sm + 3110;     // 128
  float* svw  = sm + 3238;     // 128
  float* sFk  = sm + 3366;     // 168
  float* sG   = sm + 3534;     // 168
  float* sP   = sm + 3702;     // 11
  int b = blockIdx.x, t = threadIdx.x;
  if (t < NENC) ws[OFF_DCS + b * NENC + t] = 0.f;   // zero dcs accumulator
  if (t < 10){ apad[t] = 0.f; apad[NT + 10 + t] = 0.f; }
  if (t < 512){ float2 v = ldpair<M>(prev_att, (size_t)b * 512 + t); apad[10 + 2*t] = v.x; apad[10 + 2*t + 1] = v.y; }
  for (int i = t; i < 2048; i += 1024) sUT[i] = wsc[OFF_UT + i];
  if (t < 128){ sTb[t] = wsc[OFF_TBF + t]; svw[t] = wsc[OFF_VWF + t]; }
  if (t >= 128 && t < 296) sFk[t - 128] = wsc[OFF_FKF + (t - 128)];
  if (t >= 296 && t < 464) sG[t - 296] = wsc[OFF_G + b * 168 + (t - 296)];
  if (t >= 464 && t < 475) sP[t - 464] = wsc[OFF_PF + (t - 464)];
  __syncthreads();
  float ap[21];
  #pragma unroll
  for (int k = 0; k < 21; k++) ap[k] = apad[t + k];
  float pv = 0.f;
  #pragma unroll
  for (int jj = 0; jj < 11; jj++) pv = fmaf(sP[jj], ap[jj], pv);
  pv = __logf(fmaxf(pv, 1e-6f));
  float fg[16];
  #pragma unroll
  for (int c = 0; c < 8; c++){
    float fa = 0.f, ga = 0.f;
    #pragma unroll
    for (int k = 0; k < 21; k++){
      fa = fmaf(sFk[c * 21 + k], ap[k], fa);
      ga = fmaf(sG[c * 21 + k], ap[k], ga);
    }
    fg[c] = fa; fg[8 + c] = ga;
  }
  float e = pv;
  #pragma unroll 4
  for (int m = 0; m < 128; m++){
    float h = sTb[m];
    #pragma unroll
    for (int c = 0; c < 16; c++) h = fmaf(sUT[m * 16 + c], fg[c], h);
    e = fmaf(svw[m], tanh_(h), e);
  }
  float mx = e;
  #pragma unroll
  for (int off = 1; off < 64; off <<= 1) mx = fmaxf(mx, __shfl_xor(mx, off));
  if ((t & 63) == 0) red[t >> 6] = mx;
  __syncthreads();
  if (t == 0){ float m2 = red[0]; for (int i = 1; i < 16; i++) m2 = fmaxf(m2, red[i]); bc[0] = m2; }
  __syncthreads();
  float ex = __expf(e - bc[0]);
  float smv = ex;
  #pragma unroll
  for (int off = 1; off < 64; off <<= 1) smv += __shfl_xor(smv, off);
  if ((t & 63) == 0) red[t >> 6] = smv;
  __syncthreads();
  if (t == 0){ float s2 = 0.f; for (int i = 0; i < 16; i++) s2 += red[i]; bc[1] = s2; }
  __syncthreads();
  float al = ex / bc[1];
  ws[OFF_ALPHA + b * NT + t] = al;
  st1<M>(out, OUT_ALPHA + (size_t)b * NT + t, al);
}
__global__ __launch_bounds__(1024)
void dca_e_kernel(const void* prev_att, float* ws, void* out){
  __shared__ float sm[3714];
  MODE_DISPATCH(dca_body<1>(prev_att, ws, ws, out, sm), dca_body<0>(prev_att, ws, ws, out, sm), ws)
}

// ---- dcs (HBM-bound): grid (8 chunks, 128 b), 192 thr x 4 cols, atomicAdd ----
template<int M>
__device__ __forceinline__ void dcs_body(const void* enc, float* ws, float* sA){
  int ch = blockIdx.x, b = blockIdx.y, j = threadIdx.x;
  int t0 = ch * 128;
  if (j < 128) sA[j] = ws[OFF_ALPHA + b * NT + t0 + j];
  __syncthreads();
  float a0 = 0.f, a1 = 0.f, a2 = 0.f, a3 = 0.f;
  size_t qbase = (size_t)(b * NT + t0) * (NENC / 4) + j;
  #pragma unroll 4
  for (int tl = 0; tl < 128; tl++){
    float a = sA[tl];
    float4 q = ldquad<M>(enc, qbase + (size_t)tl * (NENC / 4));
    a0 = fmaf(a, q.x, a0);
    a1 = fmaf(a, q.y, a1);
    a2 = fmaf(a, q.z, a2);
    a3 = fmaf(a, q.w, a3);
  }
  float* o = ws + OFF_DCS + (size_t)b * NENC + 4 * j;
  atomicAdd(o + 0, a0);
  atomicAdd(o + 1, a1);
  atomicAdd(o + 2, a2);
  atomicAdd(o + 3, a3);
}
__global__ __launch_bounds__(192)
void dcs_kernel(const void* enc, float* ws){
  __shared__ float sA[128];
  MODE_DISPATCH(dcs_body<1>(enc, ws, sA), dcs_body<0>(enc, ws, sA), ws)
}

// ---- lin: sx[b][j] = [dcs, h'] . lin_w[j] + lin_b[j]; grid 256, block 128 ----
// also emits the bf16 dcs output (3 cols per block)
template<int M>
__device__ __forceinline__ void lin_body(const void* __restrict__ W, const void* __restrict__ bias,
                                         float* ws, void* out){
  int j = blockIdx.x, b = threadIdx.x;
  float a = dot4<M, 0, 384>(W, (size_t)j * 512, ws + OFF_DCS, (size_t)b * 384)
          + dot4<M, 0, 128>(W, (size_t)j * 512 + 384, ws + OFF_HATTN, (size_t)b * 128)
          + ld1<M>(bias, j);
  ws[OFF_SX + b * 256 + j] = a;
  #pragma unroll
  for (int c = 0; c < 3; c++){
    int col = 3 * j + c;
    st1<M>(out, OUT_DCS + (size_t)b * 768 + col, ws[OFF_DCS + (size_t)b * 768 + col]);
  }
}
__global__ __launch_bounds__(128)
void lin_kernel(const void* W, const void* bias, float* ws, void* out){
  MODE_DISPATCH(lin_body<1>(W, bias, ws, out), lin_body<0>(W, bias, ws, out), ws)
}

// ---- GRU1/GRU2 (Kx=256 fp32 from ws, h from input); grid 256, block 128 ----
template<int M>
__device__ __forceinline__ void gru_t_body(int XOFF, int XOUT_OFF, int OUT_H,
    const void* __restrict__ h_in,
    const void* __restrict__ wih, const void* __restrict__ whh,
    const void* __restrict__ bih, const void* __restrict__ bhh,
    float* ws, void* out){
  int j = blockIdx.x, b = threadIdx.x;
  float ir = 0.f, iz = 0.f, in_ = 0.f, hr = 0.f, hz = 0.f, hn = 0.f;
  dot3<M, 0, 128>(wih, (size_t)j * 128, (size_t)(256 + j) * 128, (size_t)(512 + j) * 128,
                  ws + XOFF, (size_t)b * 128, ir, iz, in_);
  dot3<M, M, 128>(whh, (size_t)j * 128, (size_t)(256 + j) * 128, (size_t)(512 + j) * 128,
                  h_in, (size_t)b * 128, hr, hz, hn);
  float r = sigm(ir + ld1<M>(bih, j) + hr + ld1<M>(bhh, j));
  float z = sigm(iz + ld1<M>(bih, 256 + j) + hz + ld1<M>(bhh, 256 + j));
  float n = tanh_(in_ + ld1<M>(bih, 512 + j) + r * (hn + ld1<M>(bhh, 512 + j)));
  float hv = ld1<M>(h_in, (size_t)b * 256 + j);
  float hnew = (1.f - z) * n + z * hv;
  st1<M>(out, OUT_H + (size_t)b * 256 + j, hnew);
  ws[XOUT_OFF + b * 256 + j] = ws[XOFF + b * 256 + j] + hnew;
}
__global__ __launch_bounds__(128)
void gru1_kernel(const void* h_in, const void* wih, const void* whh,
                 const void* bih, const void* bhh, float* ws, void* out){
  MODE_DISPATCH(gru_t_body<1>(OFF_SX, OFF_SX2, OUT_H1, h_in, wih, whh, bih, bhh, ws, out),
                gru_t_body<0>(OFF_SX, OFF_SX2, OUT_H1, h_in, wih, whh, bih, bhh, ws, out), ws)
}
__global__ __launch_bounds__(128)
void gru2_kernel(const void* h_in, const void* wih, const void* whh,
                 const void* bih, const void* bhh, float* ws, void* out){
  MODE_DISPATCH(gru_t_body<1>(OFF_SX2, OFF_SX3, OUT_H2, h_in, wih, whh, bih, bhh, ws, out),
                gru_t_body<0>(OFF_SX2, OFF_SX3, OUT_H2, h_in, wih, whh, bih, bhh, ws, out), ws)
}

// ---- proj: mel[b][j] = sx3[b] . proj_w[j] + proj_b[j]; grid 400, block 128 ----
template<int M>
__device__ __forceinline__ void proj_body(const void* __restrict__ W, const void* __restrict__ bias,
                                          float* ws, void* out){
  int j = blockIdx.x, b = threadIdx.x;
  float a = dot4<M, 0, 128>(W, (size_t)j * 128, ws + OFF_SX3, (size_t)b * 128) + ld1<M>(bias, j);
  st1<M>(out, OUT_MEL + (size_t)b * NMELS + j, a);
}
__global__ __launch_bounds__(128)
void proj_kernel(const void* W, const void* bias, float* ws, void* out){
  MODE_DISPATCH(proj_body<1>(W, bias, ws, out), proj_body<0>(W, bias, ws, out), ws)
}

extern "C" void kernel_launch(void* const* d_in, const int* in_sizes, int n_in,
                              void* d_out, int out_size, void* d_ws, size_t ws_size,
                              hipStream_t stream){
  (void)in_sizes; (void)n_in; (void)out_size; (void)ws_size;
  const void* enc       = d_in[0];
  const void* prev_frame= d_in[1];
  const void* prev_att  = d_in[2];
  const void* dcs_state = d_in[3];
  const void* h_att     = d_in[4];
  const void* h1        = d_in[5];
  const void* h2        = d_in[6];
  const void* pre_w1    = d_in[7];
  const void* pre_b1    = d_in[8];
  const void* pre_w2    = d_in[9];
  const void* pre_b2    = d_in[10];
  const void* dca_Ww    = d_in[11];
  const void* dca_Wb    = d_in[12];
  const void* dca_Vw    = d_in[13];
  const void* dca_Fk    = d_in[14];
  const void* dca_Uw    = d_in[15];
  const void* dca_Tw    = d_in[16];
  const void* dca_Tb    = d_in[17];
  const void* dca_vw    = d_in[18];
  const void* att_wih   = d_in[19];
  const void* att_whh   = d_in[20];
  const void* att_bih   = d_in[21];
  const void* att_bhh   = d_in[22];
  const void* lin_w     = d_in[23];
  const void* lin_b     = d_in[24];
  const void* r1_wih    = d_in[25];
  const void* r1_whh    = d_in[26];
  const void* r1_bih    = d_in[27];
  const void* r1_bhh    = d_in[28];
  const void* r2_wih    = d_in[29];
  const void* r2_whh    = d_in[30];
  const void* r2_bih    = d_in[31];
  const void* r2_bhh    = d_in[32];
  const void* proj_w    = d_in[33];
  const void* proj_b    = d_in[34];
  const void* P         = d_in[35];
  float* ws = (float*)d_ws;
  void* out = d_out;

  prep_kernel<<<1, 256, 0, stream>>>(enc, dca_Uw, dca_Tw, dca_Tb, dca_vw, dca_Fk, P, ws);
  pre1_kernel<<<256, 128, 0, stream>>>(prev_frame, pre_w1, pre_b1, ws);
  pre2_kernel<<<128, 128, 0, stream>>>(pre_w2, pre_b2, ws);
  gru_att_kernel<<<256, 128, 0, stream>>>(dcs_state, h_att, att_wih, att_whh, att_bih, att_bhh, ws, out);
  ww_kernel<<<128, 128, 0, stream>>>(dca_Ww, dca_Wb, ws);
  vw_kernel<<<168, 128, 0, stream>>>(dca_Vw, ws);
  dca_e_kernel<<<NB, 1024, 0, stream>>>(prev_att, ws, out);
  dcs_kernel<<<dim3(8, NB), 192, 0, stream>>>(enc, ws);
  lin_kernel<<<256, 128, 0, stream>>>(lin_w, lin_b, ws, out);
  gru1_kernel<<<256, 128, 0, stream>>>(h1, r1_wih, r1_whh, r1_bih, r1_bhh, ws, out);
  gru2_kernel<<<256, 128, 0, stream>>>(h2, r2_wih, r2_whh, r2_bih, r2_bhh, ws, out);
  proj_kernel<<<400, 128, 0, stream>>>(proj_w, proj_b, ws, out);
}